// Round 8
// baseline (893.654 us; speedup 1.0000x reference)
//
#include <hip/hip_runtime.h>

// MultiScalePointNet — R8: R5 base (PPB=32, 2 blocks/CU structural) +
// packed-f16 L1 (v_pk_fma_f16, ~2x fewer L1 VALU ops) + bank-conflict-free
// LDS strides (H1S 72->76, H2S 136->140, XIS 264->268: dword stride = 6 mod 32
// -> 16 distinct banks over m16; old strides were 4 mod 32 -> m16/m16+8 alias).
// Transposed MFMA GEMMs; packed b64 epilogues; 5-neighbor chunks; max-pool in
// registers; sw1 accumulated across scales in persistent C-frags.

typedef _Float16 f16x8 __attribute__((ext_vector_type(8)));
typedef _Float16 f16x4 __attribute__((ext_vector_type(4)));
typedef _Float16 f16x2 __attribute__((ext_vector_type(2)));
typedef __fp16   h16x2 __attribute__((ext_vector_type(2)));   // cvt_pkrtz return type
typedef float    f32x4 __attribute__((ext_vector_type(4)));

#define PPB 32
#define KMAX 20

// d_ws offsets (halves)
#define PW2OFF 0
#define PW3OFF 24576
#define SW1OFF 122880
#define SW2OFF 319488
#define SW3OFF 352256
#define SW4OFF 360448
#define PW1HOFF 362496      // packed pw1: [3][32] f16x8 = 768 halves
#define NFRAGS 708

// LDS layout (bytes)
#define NB_OFF 0            // nbf f32 [640][4] = 10240 ; later h3 f16 [32][140] = 8960
#define H1_OFF 10240        // h1 f16 [160][76] = 24320 ; later x2 f16 [32][268] = 17152
#define H2_OFF 34560        // h2 f16 [160][140] = 44800 ; later xi f16 [32][268],
                            //   h4 f16 [32][76] = 4864, out4 f32 [32][36] @ +8192
#define PW1H_OFF 79360      // pw1h f16 [32] x f16x8 = 512 B
#define LDS_BYTES 79872
#define H1S 76
#define H2S 140
#define XIS 268
#define X2S 268
#define H3S 140
#define H4S 76
#define O4S 36

__device__ __forceinline__ float leakyf(float x) { return fmaxf(x, 0.2f * x); }

__device__ __forceinline__ f16x4 pkrtz4(f32x4 a) {   // packed RTZ f32x4 -> f16x4
    h16x2 lo = __builtin_amdgcn_cvt_pkrtz(a[0], a[1]);
    h16x2 hi = __builtin_amdgcn_cvt_pkrtz(a[2], a[3]);
    f16x4 r;
    r[0] = (_Float16)lo[0]; r[1] = (_Float16)lo[1];
    r[2] = (_Float16)hi[0]; r[3] = (_Float16)hi[1];
    return r;
}
__device__ __forceinline__ f16x4 leaky4h(f16x4 h) {  // v_pk_mul + v_pk_max
    f16x4 s = h * (_Float16)0.2f;
    return __builtin_elementwise_max(h, s);
}
__device__ __forceinline__ f16x4 rne4(f32x4 a) {     // RNE for accuracy-critical stores
    f16x4 r; r[0] = (_Float16)a[0]; r[1] = (_Float16)a[1];
    r[2] = (_Float16)a[2]; r[3] = (_Float16)a[3];
    return r;
}
__device__ __forceinline__ f32x4 ldbias4(const float* b) {
    float4 t = *(const float4*)b;
    return (f32x4){t.x, t.y, t.z, t.w};
}

// ---------------- prep: swizzle weights to fragment-major fp16 ----------------
struct PrepRegion { const float* src; int inC; int Kk; int fEnd; int dstOff; };
struct PrepParams {
    PrepRegion r[10];
    const float* pw1; const float* pb1;
    _Float16* dst;
};

__global__ __launch_bounds__(256) void prep_kernel(PrepParams pp) {
    int gid = blockIdx.x * 256 + threadIdx.x;
    if (gid < NFRAGS * 64) {
        int f = gid >> 6, L = gid & 63;
        int ri = 0;
        while (f >= pp.r[ri].fEnd) ri++;
        int f0 = (ri == 0) ? 0 : pp.r[ri - 1].fEnd;
        const PrepRegion R = pp.r[ri];
        int fl = f - f0;
        int nt = fl / R.Kk, kk = fl - nt * R.Kk;
        int row = nt * 16 + (L & 15);
        int col = kk * 32 + (L >> 4) * 8;
        const float* s = R.src + row * R.inC + col;
        f16x8 v;
#pragma unroll
        for (int j = 0; j < 8; ++j) v[j] = (_Float16)s[j];
        *(f16x8*)(pp.dst + R.dstOff + fl * 512 + L * 8) = v;
    } else if (gid < NFRAGS * 64 + 96) {
        // pw1 packed channel-pairs: (wx0,wx1, wy0,wy1, wz0,wz1, b0,b1)
        int t = gid - NFRAGS * 64;
        int i = t >> 5, pr = t & 31;
        int c0 = pr * 2, c1 = pr * 2 + 1;
        f16x8 v;
        v[0] = (_Float16)pp.pw1[i * 192 + c0 * 3 + 0];
        v[1] = (_Float16)pp.pw1[i * 192 + c1 * 3 + 0];
        v[2] = (_Float16)pp.pw1[i * 192 + c0 * 3 + 1];
        v[3] = (_Float16)pp.pw1[i * 192 + c1 * 3 + 1];
        v[4] = (_Float16)pp.pw1[i * 192 + c0 * 3 + 2];
        v[5] = (_Float16)pp.pw1[i * 192 + c1 * 3 + 2];
        v[6] = (_Float16)pp.pb1[i * 64 + c0];
        v[7] = (_Float16)pp.pb1[i * 64 + c1];
        *(f16x8*)(pp.dst + PW1HOFF + (i * 32 + pr) * 8) = v;
    }
}

// ---------------- main kernel ----------------
struct MainParams {
    const float* points; const int* nidx;
    const float* pb2; const float* pb3;
    const float* sb1; const float* sb2; const float* sb3; const float* sb4;
    const float* sw5; const float* sb5;
    const _Float16* wsH;
    float* out;
    int n;
};

__global__ __launch_bounds__(256, 2) void msp_mfma(MainParams p) {
    __shared__ __align__(16) unsigned char pool[LDS_BYTES];
    float*    nbf = (float*)(pool + NB_OFF);        // [640][4] f32
    _Float16* h1  = (_Float16*)(pool + H1_OFF);     // [160][76]
    _Float16* h2  = (_Float16*)(pool + H2_OFF);     // [160][140]
    _Float16* xi  = (_Float16*)(pool + H2_OFF);     // [32][268] (aliases h2)
    _Float16* x2  = (_Float16*)(pool + H1_OFF);     // [32][268] (aliases h1)
    _Float16* h3  = (_Float16*)(pool + NB_OFF);     // [32][140] (aliases nbf)
    _Float16* h4  = (_Float16*)(pool + H2_OFF);     // [32][76]  (aliases h2/xi)
    float*    out4= (float*)(pool + H2_OFF + 8192); // [32][36] f32
    _Float16* pw1h= (_Float16*)(pool + PW1H_OFF);   // [32] f16x8

    const int tid  = threadIdx.x;
    const int wave = tid >> 6, lane = tid & 63;
    const int q = lane >> 4, m16 = lane & 15;
    const int n0 = blockIdx.x * PPB;

    // ---- gather: nb rows r = k*32 + p, xyz1
    for (int r = tid; r < PPB * KMAX; r += 256) {
        int pp_ = r & 31, k = r >> 5;
        int idx = p.nidx[(n0 + pp_) * KMAX + k];
        const float* npt = p.points + idx * 3;
        const float* cpt = p.points + (n0 + pp_) * 3;
        float4 v;
        v.x = npt[0] - cpt[0];
        v.y = npt[1] - cpt[1];
        v.z = npt[2] - cpt[2];
        v.w = 1.0f;
        ((float4*)nbf)[r] = v;
    }

    // persistent sw1 accumulators, bias in C-init (once)
    f32x4 accC[2][4];
#pragma unroll
    for (int mt = 0; mt < 4; ++mt) {
        f32x4 b = ldbias4(p.sb1 + (wave * 4 + mt) * 16 + q * 4);
        accC[0][mt] = b; accC[1][mt] = b;
    }
    __syncthreads();

    const int NC[3] = {1, 2, 4};
    for (int i = 0; i < 3; ++i) {
        // ---- stage packed pw1 pairs; hoist per-scale W2/W3 frags + b2
        if (tid < 32)
            ((f16x8*)pw1h)[tid] = ((const f16x8*)(p.wsH + PW1HOFF))[i * 32 + tid];

        f16x8 W2f[2][2], W3f[4][4];
#pragma unroll
        for (int mt = 0; mt < 2; ++mt)
#pragma unroll
            for (int kk = 0; kk < 2; ++kk)
                W2f[mt][kk] = *(const f16x8*)(p.wsH + PW2OFF +
                    (i * 16 + (wave * 2 + mt) * 2 + kk) * 512 + lane * 8);
#pragma unroll
        for (int mt = 0; mt < 4; ++mt)
#pragma unroll
            for (int kk = 0; kk < 4; ++kk)
                W3f[mt][kk] = *(const f16x8*)(p.wsH + PW3OFF +
                    (i * 64 + (wave * 4 + mt) * 4 + kk) * 512 + lane * 8);

        f32x4 b2v[2];
#pragma unroll
        for (int mt = 0; mt < 2; ++mt)
            b2v[mt] = ldbias4(p.pb2 + i * 128 + (wave * 2 + mt) * 16 + q * 4);

        f32x4 maxC[2][4];
#pragma unroll
        for (int pt = 0; pt < 2; ++pt)
#pragma unroll
            for (int mt = 0; mt < 4; ++mt)
                maxC[pt][mt] = (f32x4){-3.0e38f, -3.0e38f, -3.0e38f, -3.0e38f};

        __syncthreads();   // pw1h ready; prev scale's xi readers done

        for (int c = 0; c < NC[i]; ++c) {
            const int k0 = c * 5;
            // ---- L1 (packed f16): 160 rows x 64 ch -> h1
            {
                int p_ = tid & 31, g = tid >> 5;   // point, channel-octet
#pragma unroll
                for (int kc = 0; kc < 5; ++kc) {
                    float4 nv = ((const float4*)nbf)[(k0 + kc) * 32 + p_];
                    f16x2 X; X[0] = X[1] = (_Float16)nv.x;
                    f16x2 Y; Y[0] = Y[1] = (_Float16)nv.y;
                    f16x2 Z; Z[0] = Z[1] = (_Float16)nv.z;
                    f16x8 hv;
#pragma unroll
                    for (int j = 0; j < 4; ++j) {
                        f16x8 w8 = ((const f16x8*)pw1h)[g * 4 + j];
                        f16x2 wx = {w8[0], w8[1]}, wy = {w8[2], w8[3]};
                        f16x2 wz = {w8[4], w8[5]}, wb = {w8[6], w8[7]};
                        f16x2 v = wx * X + wy * Y + wz * Z + wb;
                        f16x2 s = v * (_Float16)0.2f;
                        v = __builtin_elementwise_max(v, s);
                        hv[2 * j] = v[0]; hv[2 * j + 1] = v[1];
                    }
                    *(f16x8*)(h1 + (kc * 32 + p_) * H1S + g * 8) = hv;
                }
            }
            __syncthreads();

            // ---- L2: W2 x h1^T -> h2[row][128]  (packed b64 epilogue)
            for (int nt = 0; nt < 10; ++nt) {
                const _Float16* br = h1 + (nt * 16 + m16) * H1S + q * 8;
                f16x8 b0 = *(const f16x8*)br;
                f16x8 b1 = *(const f16x8*)(br + 32);
                f32x4 acc0 = __builtin_amdgcn_mfma_f32_16x16x32_f16(W2f[0][0], b0, b2v[0], 0, 0, 0);
                f32x4 acc1 = __builtin_amdgcn_mfma_f32_16x16x32_f16(W2f[1][0], b0, b2v[1], 0, 0, 0);
                acc0 = __builtin_amdgcn_mfma_f32_16x16x32_f16(W2f[0][1], b1, acc0, 0, 0, 0);
                acc1 = __builtin_amdgcn_mfma_f32_16x16x32_f16(W2f[1][1], b1, acc1, 0, 0, 0);
                _Float16* wr = h2 + (nt * 16 + m16) * H2S + q * 4;
                *(f16x4*)(wr + (wave * 2 + 0) * 16) = leaky4h(pkrtz4(acc0));
                *(f16x4*)(wr + (wave * 2 + 1) * 16) = leaky4h(pkrtz4(acc1));
            }
            __syncthreads();

            // ---- L3: W3 x h2^T -> max-fold into maxC (pb3 at epilogue)
            for (int nt = 0; nt < 10; ++nt) {
                const _Float16* br = h2 + (nt * 16 + m16) * H2S + q * 8;
                f16x8 b[4];
#pragma unroll
                for (int kk = 0; kk < 4; ++kk) b[kk] = *(const f16x8*)(br + kk * 32);
                f32x4 acc[4];
#pragma unroll
                for (int mt = 0; mt < 4; ++mt)
                    acc[mt] = __builtin_amdgcn_mfma_f32_16x16x32_f16(W3f[mt][0], b[0],
                              (f32x4){0.f, 0.f, 0.f, 0.f}, 0, 0, 0);
#pragma unroll
                for (int kk = 1; kk < 4; ++kk)
#pragma unroll
                    for (int mt = 0; mt < 4; ++mt)
                        acc[mt] = __builtin_amdgcn_mfma_f32_16x16x32_f16(W3f[mt][kk], b[kk], acc[mt], 0, 0, 0);
                int pt = nt & 1;
#pragma unroll
                for (int mt = 0; mt < 4; ++mt)
                    maxC[pt][mt] = __builtin_elementwise_max(maxC[pt][mt], acc[mt]);
            }
            // next L1 writes h1 only -> safe without barrier
        }

        // ---- xi = maxC + pb3 -> LDS (aliases h2: barrier first)
        __syncthreads();
#pragma unroll
        for (int pt = 0; pt < 2; ++pt)
#pragma unroll
            for (int mt = 0; mt < 4; ++mt) {
                f32x4 b3 = ldbias4(p.pb3 + i * 256 + (wave * 4 + mt) * 16 + q * 4);
                *(f16x4*)(xi + (pt * 16 + m16) * XIS + (wave * 4 + mt) * 16 + q * 4)
                    = rne4(maxC[pt][mt] + b3);
            }
        __syncthreads();

        // ---- sw1 partial: accC += SW1[:, scale-i slice] x xi^T
        for (int nt = 0; nt < 2; ++nt) {
            const _Float16* br = xi + (nt * 16 + m16) * XIS + q * 8;
            f16x8 bf[8];
#pragma unroll
            for (int kk = 0; kk < 8; ++kk) bf[kk] = *(const f16x8*)(br + kk * 32);
#pragma unroll
            for (int kk = 0; kk < 8; ++kk)
#pragma unroll
                for (int mt = 0; mt < 4; ++mt) {
                    f16x8 a = *(const f16x8*)(p.wsH + SW1OFF +
                        ((wave * 4 + mt) * 24 + i * 8 + kk) * 512 + lane * 8);
                    accC[nt][mt] = __builtin_amdgcn_mfma_f32_16x16x32_f16(a, bf[kk], accC[nt][mt], 0, 0, 0);
                }
        }
        // xi reads complete before next scale's pre-L1 barrier -> safe
    }

    // ---- x2 = leaky(accC) -> LDS (aliases h1; h1 readers long past)
#pragma unroll
    for (int nt = 0; nt < 2; ++nt)
#pragma unroll
        for (int mt = 0; mt < 4; ++mt) {
            f32x4 v = accC[nt][mt];
#pragma unroll
            for (int r = 0; r < 4; ++r) v[r] = leakyf(v[r]);
            *(f16x4*)(x2 + (nt * 16 + m16) * X2S + (wave * 4 + mt) * 16 + q * 4) = rne4(v);
        }
    __syncthreads();

    // ---- sw2: [256 -> 128]
    for (int nt = 0; nt < 2; ++nt) {
        const _Float16* br = x2 + (nt * 16 + m16) * X2S + q * 8;
        f16x8 bf[8];
#pragma unroll
        for (int kk = 0; kk < 8; ++kk) bf[kk] = *(const f16x8*)(br + kk * 32);
        f32x4 acc[2];
#pragma unroll
        for (int mt = 0; mt < 2; ++mt)
            acc[mt] = ldbias4(p.sb2 + (wave * 2 + mt) * 16 + q * 4);
#pragma unroll
        for (int kk = 0; kk < 8; ++kk)
#pragma unroll
            for (int mt = 0; mt < 2; ++mt) {
                f16x8 a = *(const f16x8*)(p.wsH + SW2OFF +
                    ((wave * 2 + mt) * 8 + kk) * 512 + lane * 8);
                acc[mt] = __builtin_amdgcn_mfma_f32_16x16x32_f16(a, bf[kk], acc[mt], 0, 0, 0);
            }
#pragma unroll
        for (int mt = 0; mt < 2; ++mt) {
            f32x4 v = acc[mt];
#pragma unroll
            for (int r = 0; r < 4; ++r) v[r] = leakyf(v[r]);
            *(f16x4*)(h3 + (nt * 16 + m16) * H3S + (wave * 2 + mt) * 16 + q * 4) = rne4(v);
        }
    }
    __syncthreads();

    // ---- sw3: [128 -> 64]  (m-tile = wave)
    for (int nt = 0; nt < 2; ++nt) {
        const _Float16* br = h3 + (nt * 16 + m16) * H3S + q * 8;
        f32x4 acc = ldbias4(p.sb3 + wave * 16 + q * 4);
#pragma unroll
        for (int kk = 0; kk < 4; ++kk) {
            f16x8 bf = *(const f16x8*)(br + kk * 32);
            f16x8 a = *(const f16x8*)(p.wsH + SW3OFF + (wave * 4 + kk) * 512 + lane * 8);
            acc = __builtin_amdgcn_mfma_f32_16x16x32_f16(a, bf, acc, 0, 0, 0);
        }
#pragma unroll
        for (int r = 0; r < 4; ++r) acc[r] = leakyf(acc[r]);
        *(f16x4*)(h4 + (nt * 16 + m16) * H4S + wave * 16 + q * 4) = rne4(acc);
    }
    __syncthreads();

    // ---- sw4: [64 -> 32]  (waves 0,1)
    if (wave < 2) {
        for (int nt = 0; nt < 2; ++nt) {
            const _Float16* br = h4 + (nt * 16 + m16) * H4S + q * 8;
            f32x4 acc = ldbias4(p.sb4 + wave * 16 + q * 4);
#pragma unroll
            for (int kk = 0; kk < 2; ++kk) {
                f16x8 bf = *(const f16x8*)(br + kk * 32);
                f16x8 a = *(const f16x8*)(p.wsH + SW4OFF + (wave * 2 + kk) * 512 + lane * 8);
                acc = __builtin_amdgcn_mfma_f32_16x16x32_f16(a, bf, acc, 0, 0, 0);
            }
#pragma unroll
            for (int r = 0; r < 4; ++r) acc[r] = leakyf(acc[r]);
            *(f32x4*)(out4 + (nt * 16 + m16) * O4S + wave * 16 + q * 4) = acc;
        }
    }
    __syncthreads();

    // ---- sw5: [32 -> 1]
    if (tid < PPB) {
        float acc = p.sb5[0];
#pragma unroll
        for (int c = 0; c < 32; ++c)
            acc = fmaf(out4[tid * O4S + c], p.sw5[c], acc);
        p.out[n0 + tid] = acc;
    }
}

// ---------------- launch ----------------
extern "C" void kernel_launch(void* const* d_in, const int* in_sizes, int n_in,
                              void* d_out, int out_size, void* d_ws, size_t ws_size,
                              hipStream_t stream) {
    const float* points = (const float*)d_in[0];
    const int*   nidx   = (const int*)d_in[1];
    const float* pw1 = (const float*)d_in[2];  const float* pb1 = (const float*)d_in[3];
    const float* pw2 = (const float*)d_in[4];  const float* pb2 = (const float*)d_in[5];
    const float* pw3 = (const float*)d_in[6];  const float* pb3 = (const float*)d_in[7];
    const float* sw1 = (const float*)d_in[8];  const float* sb1 = (const float*)d_in[9];
    const float* sw2 = (const float*)d_in[10]; const float* sb2 = (const float*)d_in[11];
    const float* sw3 = (const float*)d_in[12]; const float* sb3 = (const float*)d_in[13];
    const float* sw4 = (const float*)d_in[14]; const float* sb4 = (const float*)d_in[15];
    const float* sw5 = (const float*)d_in[16]; const float* sb5 = (const float*)d_in[17];

    _Float16* wsH = (_Float16*)d_ws;

    PrepParams pp;
    for (int i = 0; i < 3; ++i)
        pp.r[i] = { pw2 + i * 8192, 64, 2, 16 * (i + 1), PW2OFF + i * 8192 };
    for (int i = 0; i < 3; ++i)
        pp.r[3 + i] = { pw3 + i * 32768, 128, 4, 48 + 64 * (i + 1), PW3OFF + i * 32768 };
    pp.r[6] = { sw1, 768, 24, 624, SW1OFF };
    pp.r[7] = { sw2, 256, 8, 688, SW2OFF };
    pp.r[8] = { sw3, 128, 4, 704, SW3OFF };
    pp.r[9] = { sw4, 64, 2, 708, SW4OFF };
    pp.pw1 = pw1; pp.pb1 = pb1;
    pp.dst = wsH;

    int prep_threads = NFRAGS * 64 + 96;
    hipLaunchKernelGGL(prep_kernel, dim3((prep_threads + 255) / 256), dim3(256), 0, stream, pp);

    MainParams mp;
    mp.points = points; mp.nidx = nidx;
    mp.pb2 = pb2; mp.pb3 = pb3;
    mp.sb1 = sb1; mp.sb2 = sb2; mp.sb3 = sb3; mp.sb4 = sb4;
    mp.sw5 = sw5; mp.sb5 = sb5;
    mp.wsH = wsH;
    mp.out = (float*)d_out;
    mp.n = in_sizes[0] / 3;

    int blocks = mp.n / PPB;   // 100000/32 = 3125
    hipLaunchKernelGGL(msp_mfma, dim3(blocks), dim3(256), 0, stream, mp);
}

// Round 10
// 421.544 us; speedup vs baseline: 2.1200x; 2.1200x over previous
//
#include <hip/hip_runtime.h>

// MultiScalePointNet — R10: R9 (R5 16B-aligned layout + packed-f16 L1) with
// FULL barrier hygiene. R9 diverged post-timing (absmax 9.8e-4, timing-
// dependent) — the two barrier elisions (L3->next L1, sw1->next scale) are
// the prime suspects and are restored here. All other structure identical.

typedef _Float16 f16x8 __attribute__((ext_vector_type(8)));
typedef _Float16 f16x4 __attribute__((ext_vector_type(4)));
typedef _Float16 f16x2 __attribute__((ext_vector_type(2)));
typedef __fp16   h16x2 __attribute__((ext_vector_type(2)));   // cvt_pkrtz return type
typedef float    f32x4 __attribute__((ext_vector_type(4)));

#define PPB 32
#define KMAX 20

// d_ws offsets (halves)
#define PW2OFF 0
#define PW3OFF 24576
#define SW1OFF 122880
#define SW2OFF 319488
#define SW3OFF 352256
#define SW4OFF 360448
#define PW1HOFF 362496      // packed pw1: [3][32] f16x8 = 768 halves
#define NFRAGS 708

// LDS layout (bytes) — R5 geometry (16B-aligned strides)
#define NB_OFF 0            // nbf f32 [640][4] = 10240 ; later h3 f16 [32][136]
#define H1_OFF 10240        // h1 f16 [160][72] = 23040 ; later x2 f16 [32][264]
#define H2_OFF 33280        // h2 f16 [160][136] = 43520 ; later xi f16 [32][264],
                            //   h4 f16 [32][72], out4 f32 [32][36] @ +8192
#define PW1H_OFF 76800      // pw1h f16 [32] x f16x8 = 512 B
#define LDS_BYTES 77312
#define H1S 72
#define H2S 136
#define XIS 264
#define X2S 264
#define H3S 136
#define H4S 72
#define O4S 36

__device__ __forceinline__ float leakyf(float x) { return fmaxf(x, 0.2f * x); }

__device__ __forceinline__ f16x4 pkrtz4(f32x4 a) {   // packed RTZ f32x4 -> f16x4
    h16x2 lo = __builtin_amdgcn_cvt_pkrtz(a[0], a[1]);
    h16x2 hi = __builtin_amdgcn_cvt_pkrtz(a[2], a[3]);
    f16x4 r;
    r[0] = (_Float16)lo[0]; r[1] = (_Float16)lo[1];
    r[2] = (_Float16)hi[0]; r[3] = (_Float16)hi[1];
    return r;
}
__device__ __forceinline__ f16x4 leaky4h(f16x4 h) {  // v_pk_mul + v_pk_max
    f16x4 s = h * (_Float16)0.2f;
    return __builtin_elementwise_max(h, s);
}
__device__ __forceinline__ f16x4 rne4(f32x4 a) {     // RNE for accuracy-critical stores
    f16x4 r; r[0] = (_Float16)a[0]; r[1] = (_Float16)a[1];
    r[2] = (_Float16)a[2]; r[3] = (_Float16)a[3];
    return r;
}
__device__ __forceinline__ f32x4 ldbias4(const float* b) {
    float4 t = *(const float4*)b;
    return (f32x4){t.x, t.y, t.z, t.w};
}

// ---------------- prep: swizzle weights to fragment-major fp16 ----------------
struct PrepRegion { const float* src; int inC; int Kk; int fEnd; int dstOff; };
struct PrepParams {
    PrepRegion r[10];
    const float* pw1; const float* pb1;
    _Float16* dst;
};

__global__ __launch_bounds__(256) void prep_kernel(PrepParams pp) {
    int gid = blockIdx.x * 256 + threadIdx.x;
    if (gid < NFRAGS * 64) {
        int f = gid >> 6, L = gid & 63;
        int ri = 0;
        while (f >= pp.r[ri].fEnd) ri++;
        int f0 = (ri == 0) ? 0 : pp.r[ri - 1].fEnd;
        const PrepRegion R = pp.r[ri];
        int fl = f - f0;
        int nt = fl / R.Kk, kk = fl - nt * R.Kk;
        int row = nt * 16 + (L & 15);
        int col = kk * 32 + (L >> 4) * 8;
        const float* s = R.src + row * R.inC + col;
        f16x8 v;
#pragma unroll
        for (int j = 0; j < 8; ++j) v[j] = (_Float16)s[j];
        *(f16x8*)(pp.dst + R.dstOff + fl * 512 + L * 8) = v;
    } else if (gid < NFRAGS * 64 + 96) {
        // pw1 packed channel-pairs: (wx0,wx1, wy0,wy1, wz0,wz1, b0,b1)
        int t = gid - NFRAGS * 64;
        int i = t >> 5, pr = t & 31;
        int c0 = pr * 2, c1 = pr * 2 + 1;
        f16x8 v;
        v[0] = (_Float16)pp.pw1[i * 192 + c0 * 3 + 0];
        v[1] = (_Float16)pp.pw1[i * 192 + c1 * 3 + 0];
        v[2] = (_Float16)pp.pw1[i * 192 + c0 * 3 + 1];
        v[3] = (_Float16)pp.pw1[i * 192 + c1 * 3 + 1];
        v[4] = (_Float16)pp.pw1[i * 192 + c0 * 3 + 2];
        v[5] = (_Float16)pp.pw1[i * 192 + c1 * 3 + 2];
        v[6] = (_Float16)pp.pb1[i * 64 + c0];
        v[7] = (_Float16)pp.pb1[i * 64 + c1];
        *(f16x8*)(pp.dst + PW1HOFF + (i * 32 + pr) * 8) = v;
    }
}

// ---------------- main kernel ----------------
struct MainParams {
    const float* points; const int* nidx;
    const float* pb2; const float* pb3;
    const float* sb1; const float* sb2; const float* sb3; const float* sb4;
    const float* sw5; const float* sb5;
    const _Float16* wsH;
    float* out;
    int n;
};

__global__ __launch_bounds__(256, 2) void msp_mfma(MainParams p) {
    __shared__ __align__(16) unsigned char pool[LDS_BYTES];
    float*    nbf = (float*)(pool + NB_OFF);        // [640][4] f32
    _Float16* h1  = (_Float16*)(pool + H1_OFF);     // [160][72]
    _Float16* h2  = (_Float16*)(pool + H2_OFF);     // [160][136]
    _Float16* xi  = (_Float16*)(pool + H2_OFF);     // [32][264] (aliases h2)
    _Float16* x2  = (_Float16*)(pool + H1_OFF);     // [32][264] (aliases h1)
    _Float16* h3  = (_Float16*)(pool + NB_OFF);     // [32][136] (aliases nbf)
    _Float16* h4  = (_Float16*)(pool + H2_OFF);     // [32][72]  (aliases h2/xi)
    float*    out4= (float*)(pool + H2_OFF + 8192); // [32][36] f32
    _Float16* pw1h= (_Float16*)(pool + PW1H_OFF);   // [32] f16x8

    const int tid  = threadIdx.x;
    const int wave = tid >> 6, lane = tid & 63;
    const int q = lane >> 4, m16 = lane & 15;
    const int n0 = blockIdx.x * PPB;

    // ---- gather: nb rows r = k*32 + p, xyz1
    for (int r = tid; r < PPB * KMAX; r += 256) {
        int pp_ = r & 31, k = r >> 5;
        int idx = p.nidx[(n0 + pp_) * KMAX + k];
        const float* npt = p.points + idx * 3;
        const float* cpt = p.points + (n0 + pp_) * 3;
        float4 v;
        v.x = npt[0] - cpt[0];
        v.y = npt[1] - cpt[1];
        v.z = npt[2] - cpt[2];
        v.w = 1.0f;
        ((float4*)nbf)[r] = v;
    }

    // persistent sw1 accumulators, bias in C-init (once)
    f32x4 accC[2][4];
#pragma unroll
    for (int mt = 0; mt < 4; ++mt) {
        f32x4 b = ldbias4(p.sb1 + (wave * 4 + mt) * 16 + q * 4);
        accC[0][mt] = b; accC[1][mt] = b;
    }
    __syncthreads();

    const int NC[3] = {1, 2, 4};
    for (int i = 0; i < 3; ++i) {
        // ---- stage packed pw1 pairs; hoist per-scale W2/W3 frags + b2
        if (tid < 32)
            ((f16x8*)pw1h)[tid] = ((const f16x8*)(p.wsH + PW1HOFF))[i * 32 + tid];

        f16x8 W2f[2][2], W3f[4][4];
#pragma unroll
        for (int mt = 0; mt < 2; ++mt)
#pragma unroll
            for (int kk = 0; kk < 2; ++kk)
                W2f[mt][kk] = *(const f16x8*)(p.wsH + PW2OFF +
                    (i * 16 + (wave * 2 + mt) * 2 + kk) * 512 + lane * 8);
#pragma unroll
        for (int mt = 0; mt < 4; ++mt)
#pragma unroll
            for (int kk = 0; kk < 4; ++kk)
                W3f[mt][kk] = *(const f16x8*)(p.wsH + PW3OFF +
                    (i * 64 + (wave * 4 + mt) * 4 + kk) * 512 + lane * 8);

        f32x4 b2v[2];
#pragma unroll
        for (int mt = 0; mt < 2; ++mt)
            b2v[mt] = ldbias4(p.pb2 + i * 128 + (wave * 2 + mt) * 16 + q * 4);

        f32x4 maxC[2][4];
#pragma unroll
        for (int pt = 0; pt < 2; ++pt)
#pragma unroll
            for (int mt = 0; mt < 4; ++mt)
                maxC[pt][mt] = (f32x4){-3.0e38f, -3.0e38f, -3.0e38f, -3.0e38f};

        __syncthreads();   // pw1h ready

        for (int c = 0; c < NC[i]; ++c) {
            const int k0 = c * 5;
            // ---- L1 (packed f16): 160 rows x 64 ch -> h1
            {
                int p_ = tid & 31, g = tid >> 5;   // point, channel-octet
#pragma unroll
                for (int kc = 0; kc < 5; ++kc) {
                    float4 nv = ((const float4*)nbf)[(k0 + kc) * 32 + p_];
                    f16x2 X; X[0] = X[1] = (_Float16)nv.x;
                    f16x2 Y; Y[0] = Y[1] = (_Float16)nv.y;
                    f16x2 Z; Z[0] = Z[1] = (_Float16)nv.z;
                    f16x8 hv;
#pragma unroll
                    for (int j = 0; j < 4; ++j) {
                        f16x8 w8 = ((const f16x8*)pw1h)[g * 4 + j];
                        f16x2 wx = {w8[0], w8[1]}, wy = {w8[2], w8[3]};
                        f16x2 wz = {w8[4], w8[5]}, wb = {w8[6], w8[7]};
                        f16x2 v = wx * X + wy * Y + wz * Z + wb;
                        f16x2 s = v * (_Float16)0.2f;
                        v = __builtin_elementwise_max(v, s);
                        hv[2 * j] = v[0]; hv[2 * j + 1] = v[1];
                    }
                    *(f16x8*)(h1 + (kc * 32 + p_) * H1S + g * 8) = hv;
                }
            }
            __syncthreads();

            // ---- L2: W2 x h1^T -> h2[row][128]  (packed b64 epilogue)
            for (int nt = 0; nt < 10; ++nt) {
                const _Float16* br = h1 + (nt * 16 + m16) * H1S + q * 8;
                f16x8 b0 = *(const f16x8*)br;
                f16x8 b1 = *(const f16x8*)(br + 32);
                f32x4 acc0 = __builtin_amdgcn_mfma_f32_16x16x32_f16(W2f[0][0], b0, b2v[0], 0, 0, 0);
                f32x4 acc1 = __builtin_amdgcn_mfma_f32_16x16x32_f16(W2f[1][0], b0, b2v[1], 0, 0, 0);
                acc0 = __builtin_amdgcn_mfma_f32_16x16x32_f16(W2f[0][1], b1, acc0, 0, 0, 0);
                acc1 = __builtin_amdgcn_mfma_f32_16x16x32_f16(W2f[1][1], b1, acc1, 0, 0, 0);
                _Float16* wr = h2 + (nt * 16 + m16) * H2S + q * 4;
                *(f16x4*)(wr + (wave * 2 + 0) * 16) = leaky4h(pkrtz4(acc0));
                *(f16x4*)(wr + (wave * 2 + 1) * 16) = leaky4h(pkrtz4(acc1));
            }
            __syncthreads();

            // ---- L3: W3 x h2^T -> max-fold into maxC (pb3 at epilogue)
            for (int nt = 0; nt < 10; ++nt) {
                const _Float16* br = h2 + (nt * 16 + m16) * H2S + q * 8;
                f16x8 b[4];
#pragma unroll
                for (int kk = 0; kk < 4; ++kk) b[kk] = *(const f16x8*)(br + kk * 32);
                f32x4 acc[4];
#pragma unroll
                for (int mt = 0; mt < 4; ++mt)
                    acc[mt] = __builtin_amdgcn_mfma_f32_16x16x32_f16(W3f[mt][0], b[0],
                              (f32x4){0.f, 0.f, 0.f, 0.f}, 0, 0, 0);
#pragma unroll
                for (int kk = 1; kk < 4; ++kk)
#pragma unroll
                    for (int mt = 0; mt < 4; ++mt)
                        acc[mt] = __builtin_amdgcn_mfma_f32_16x16x32_f16(W3f[mt][kk], b[kk], acc[mt], 0, 0, 0);
                int pt = nt & 1;
#pragma unroll
                for (int mt = 0; mt < 4; ++mt)
                    maxC[pt][mt] = __builtin_elementwise_max(maxC[pt][mt], acc[mt]);
            }
            __syncthreads();   // R10: conservative barrier (was elided R3-R9)
        }

        // ---- xi = maxC + pb3 -> LDS (aliases h2)
#pragma unroll
        for (int pt = 0; pt < 2; ++pt)
#pragma unroll
            for (int mt = 0; mt < 4; ++mt) {
                f32x4 b3 = ldbias4(p.pb3 + i * 256 + (wave * 4 + mt) * 16 + q * 4);
                *(f16x4*)(xi + (pt * 16 + m16) * XIS + (wave * 4 + mt) * 16 + q * 4)
                    = rne4(maxC[pt][mt] + b3);
            }
        __syncthreads();

        // ---- sw1 partial: accC += SW1[:, scale-i slice] x xi^T
        for (int nt = 0; nt < 2; ++nt) {
            const _Float16* br = xi + (nt * 16 + m16) * XIS + q * 8;
            f16x8 bf[8];
#pragma unroll
            for (int kk = 0; kk < 8; ++kk) bf[kk] = *(const f16x8*)(br + kk * 32);
#pragma unroll
            for (int kk = 0; kk < 8; ++kk)
#pragma unroll
                for (int mt = 0; mt < 4; ++mt) {
                    f16x8 a = *(const f16x8*)(p.wsH + SW1OFF +
                        ((wave * 4 + mt) * 24 + i * 8 + kk) * 512 + lane * 8);
                    accC[nt][mt] = __builtin_amdgcn_mfma_f32_16x16x32_f16(a, bf[kk], accC[nt][mt], 0, 0, 0);
                }
        }
        __syncthreads();   // R10: conservative barrier (was elided R3-R9)
    }

    // ---- x2 = leaky(accC) -> LDS (aliases h1)
#pragma unroll
    for (int nt = 0; nt < 2; ++nt)
#pragma unroll
        for (int mt = 0; mt < 4; ++mt) {
            f32x4 v = accC[nt][mt];
#pragma unroll
            for (int r = 0; r < 4; ++r) v[r] = leakyf(v[r]);
            *(f16x4*)(x2 + (nt * 16 + m16) * X2S + (wave * 4 + mt) * 16 + q * 4) = rne4(v);
        }
    __syncthreads();

    // ---- sw2: [256 -> 128]
    for (int nt = 0; nt < 2; ++nt) {
        const _Float16* br = x2 + (nt * 16 + m16) * X2S + q * 8;
        f16x8 bf[8];
#pragma unroll
        for (int kk = 0; kk < 8; ++kk) bf[kk] = *(const f16x8*)(br + kk * 32);
        f32x4 acc[2];
#pragma unroll
        for (int mt = 0; mt < 2; ++mt)
            acc[mt] = ldbias4(p.sb2 + (wave * 2 + mt) * 16 + q * 4);
#pragma unroll
        for (int kk = 0; kk < 8; ++kk)
#pragma unroll
            for (int mt = 0; mt < 2; ++mt) {
                f16x8 a = *(const f16x8*)(p.wsH + SW2OFF +
                    ((wave * 2 + mt) * 8 + kk) * 512 + lane * 8);
                acc[mt] = __builtin_amdgcn_mfma_f32_16x16x32_f16(a, bf[kk], acc[mt], 0, 0, 0);
            }
#pragma unroll
        for (int mt = 0; mt < 2; ++mt) {
            f32x4 v = acc[mt];
#pragma unroll
            for (int r = 0; r < 4; ++r) v[r] = leakyf(v[r]);
            *(f16x4*)(h3 + (nt * 16 + m16) * H3S + (wave * 2 + mt) * 16 + q * 4) = rne4(v);
        }
    }
    __syncthreads();

    // ---- sw3: [128 -> 64]  (m-tile = wave)
    for (int nt = 0; nt < 2; ++nt) {
        const _Float16* br = h3 + (nt * 16 + m16) * H3S + q * 8;
        f32x4 acc = ldbias4(p.sb3 + wave * 16 + q * 4);
#pragma unroll
        for (int kk = 0; kk < 4; ++kk) {
            f16x8 bf = *(const f16x8*)(br + kk * 32);
            f16x8 a = *(const f16x8*)(p.wsH + SW3OFF + (wave * 4 + kk) * 512 + lane * 8);
            acc = __builtin_amdgcn_mfma_f32_16x16x32_f16(a, bf, acc, 0, 0, 0);
        }
#pragma unroll
        for (int r = 0; r < 4; ++r) acc[r] = leakyf(acc[r]);
        *(f16x4*)(h4 + (nt * 16 + m16) * H4S + wave * 16 + q * 4) = rne4(acc);
    }
    __syncthreads();

    // ---- sw4: [64 -> 32]  (waves 0,1)
    if (wave < 2) {
        for (int nt = 0; nt < 2; ++nt) {
            const _Float16* br = h4 + (nt * 16 + m16) * H4S + q * 8;
            f32x4 acc = ldbias4(p.sb4 + wave * 16 + q * 4);
#pragma unroll
            for (int kk = 0; kk < 2; ++kk) {
                f16x8 bf = *(const f16x8*)(br + kk * 32);
                f16x8 a = *(const f16x8*)(p.wsH + SW4OFF + (wave * 2 + kk) * 512 + lane * 8);
                acc = __builtin_amdgcn_mfma_f32_16x16x32_f16(a, bf, acc, 0, 0, 0);
            }
#pragma unroll
            for (int r = 0; r < 4; ++r) acc[r] = leakyf(acc[r]);
            *(f32x4*)(out4 + (nt * 16 + m16) * O4S + wave * 16 + q * 4) = acc;
        }
    }
    __syncthreads();

    // ---- sw5: [32 -> 1]
    if (tid < PPB) {
        float acc = p.sb5[0];
#pragma unroll
        for (int c = 0; c < 32; ++c)
            acc = fmaf(out4[tid * O4S + c], p.sw5[c], acc);
        p.out[n0 + tid] = acc;
    }
}

// ---------------- launch ----------------
extern "C" void kernel_launch(void* const* d_in, const int* in_sizes, int n_in,
                              void* d_out, int out_size, void* d_ws, size_t ws_size,
                              hipStream_t stream) {
    const float* points = (const float*)d_in[0];
    const int*   nidx   = (const int*)d_in[1];
    const float* pw1 = (const float*)d_in[2];  const float* pb1 = (const float*)d_in[3];
    const float* pw2 = (const float*)d_in[4];  const float* pb2 = (const float*)d_in[5];
    const float* pw3 = (const float*)d_in[6];  const float* pb3 = (const float*)d_in[7];
    const float* sw1 = (const float*)d_in[8];  const float* sb1 = (const float*)d_in[9];
    const float* sw2 = (const float*)d_in[10]; const float* sb2 = (const float*)d_in[11];
    const float* sw3 = (const float*)d_in[12]; const float* sb3 = (const float*)d_in[13];
    const float* sw4 = (const float*)d_in[14]; const float* sb4 = (const float*)d_in[15];
    const float* sw5 = (const float*)d_in[16]; const float* sb5 = (const float*)d_in[17];

    _Float16* wsH = (_Float16*)d_ws;

    PrepParams pp;
    for (int i = 0; i < 3; ++i)
        pp.r[i] = { pw2 + i * 8192, 64, 2, 16 * (i + 1), PW2OFF + i * 8192 };
    for (int i = 0; i < 3; ++i)
        pp.r[3 + i] = { pw3 + i * 32768, 128, 4, 48 + 64 * (i + 1), PW3OFF + i * 32768 };
    pp.r[6] = { sw1, 768, 24, 624, SW1OFF };
    pp.r[7] = { sw2, 256, 8, 688, SW2OFF };
    pp.r[8] = { sw3, 128, 4, 704, SW3OFF };
    pp.r[9] = { sw4, 64, 2, 708, SW4OFF };
    pp.pw1 = pw1; pp.pb1 = pb1;
    pp.dst = wsH;

    int prep_threads = NFRAGS * 64 + 96;
    hipLaunchKernelGGL(prep_kernel, dim3((prep_threads + 255) / 256), dim3(256), 0, stream, pp);

    MainParams mp;
    mp.points = points; mp.nidx = nidx;
    mp.pb2 = pb2; mp.pb3 = pb3;
    mp.sb1 = sb1; mp.sb2 = sb2; mp.sb3 = sb3; mp.sb4 = sb4;
    mp.sw5 = sw5; mp.sb5 = sb5;
    mp.wsH = wsH;
    mp.out = (float*)d_out;
    mp.n = in_sizes[0] / 3;

    int blocks = mp.n / PPB;   // 100000/32 = 3125
    hipLaunchKernelGGL(msp_mfma, dim3(blocks), dim3(256), 0, stream, mp);
}